// Round 8
// baseline (384.996 us; speedup 1.0000x reference)
//
#include <hip/hip_runtime.h>

#define S_LEN 4096
#define D_MODEL 1024
#define NHEAD 16
#define DK 64
#define HID 2730
#define HIDP 2880
#define QKV_LD 3072

typedef unsigned short u16;
typedef unsigned int u32;
typedef __bf16 bf16x8 __attribute__((ext_vector_type(8)));
typedef float f32x4 __attribute__((ext_vector_type(4)));

#define MFMA16 __builtin_amdgcn_mfma_f32_16x16x32_bf16
// raw v_exp_f32 (2^x): scores bounded (|s| < ~30), no OCML guard code needed
#define EXP2 __builtin_amdgcn_exp2f

__device__ __forceinline__ float b2f(u16 u) {
    return __builtin_bit_cast(float, (u32)u << 16);
}
__device__ __forceinline__ u16 f2b(float f) {
    u32 u = __builtin_bit_cast(u32, f);
    u += 0x7FFF + ((u >> 16) & 1);
    return (u16)(u >> 16);
}
// pack two f32 -> two bf16 (truncate) in one v_perm_b32
__device__ __forceinline__ u32 pk_trunc(float lo, float hi) {
    return __builtin_amdgcn_perm(__builtin_bit_cast(u32, hi),
                                 __builtin_bit_cast(u32, lo), 0x07060302u);
}
// async global->LDS, 16B per lane; dest must be wave-uniform base + lane*16
__device__ __forceinline__ void gll16(const u16* g, u16* l) {
    __builtin_amdgcn_global_load_lds(
        (__attribute__((address_space(1))) void*)(g),
        (__attribute__((address_space(3))) void*)(l),
        16, 0, 0);
}

// ---------------------------------------------------------------------------
// Prep: 7 weight transposes (fp32->bf16, zero-pad) + rmsnorm(x, ln1) in ONE
// launch. Flat grid, 256-thread blocks. Blocks 0..12735 = tcast segments;
// blocks 12736..16831 = rmsnorm rows.  (HIDP = 2880 = 30*96)
// ---------------------------------------------------------------------------
__global__ __launch_bounds__(256)
void prep_k(const float* s0, const float* s1, const float* s2,
            const float* s3, const float* s4, const float* s5,
            const float* s6, u16* d0, u16* d1, u16* d2, u16* d3,
            u16* d4, u16* d5, u16* d6,
            const float* __restrict__ x, const float* __restrict__ ln1,
            u16* __restrict__ hb) {
    __shared__ float t[32][33];
    __shared__ float red[4];
    const int bid = blockIdx.x;
    const int tid = threadIdx.x;

    if (bid >= 12736) {   // ---- rmsnorm path ----
        const int row = bid - 12736;
        const float4 v = ((const float4*)(x + (size_t)row * D_MODEL))[tid];
        float ss = v.x * v.x + v.y * v.y + v.z * v.z + v.w * v.w;
        for (int o = 32; o; o >>= 1) ss += __shfl_down(ss, o);
        if ((tid & 63) == 0) red[tid >> 6] = ss;
        __syncthreads();
        const float tot = red[0] + red[1] + red[2] + red[3];
        const float rs = rsqrtf(tot * (1.0f / D_MODEL) + 1e-6f);
        const float4 wv = ((const float4*)ln1)[tid];
        u16* op = hb + (size_t)row * D_MODEL + tid * 4;
        u32 p0 = (u32)f2b(v.x * rs * wv.x) | ((u32)f2b(v.y * rs * wv.y) << 16);
        u32 p1 = (u32)f2b(v.z * rs * wv.z) | ((u32)f2b(v.w * rs * wv.w) << 16);
        uint2 pk; pk.x = p0; pk.y = p1;
        *(uint2*)op = pk;
        return;
    }

    // ---- transpose path ----
    const float* srcs[7] = {s0, s1, s2, s3, s4, s5, s6};
    u16* dsts[7] = {d0, d1, d2, d3, d4, d5, d6};
    const int RR[7] = {1024, 1024, 1024, 1024, 1024, 1024, 2730};
    const int CC[7] = {1024, 1024, 1024, 1024, 2730, 2730, 1024};
    const int OC[7] = {1024, 1024, 1024, 1024, 1024, 1024, 2880};
    const int XD[7] = {32, 32, 32, 32, 32, 32, 90};

    int seg, start;
    if (bid < 4096)      { seg = bid >> 10; start = seg << 10; }
    else if (bid < 6976) { seg = 4; start = 4096; }
    else if (bid < 9856) { seg = 5; start = 6976; }
    else                 { seg = 6; start = 9856; }
    const int local = bid - start;
    const int bx = local % XD[seg], byy = local / XD[seg];
    const float* in = srcs[seg];
    u16* out = dsts[seg];
    const int R = RR[seg], C = CC[seg], outC = OC[seg];

    const int r0 = byy * 32;
    const int c0 = bx * 32;
    const int tx = tid & 31, ty = tid >> 5;
#pragma unroll
    for (int j = 0; j < 4; ++j) {
        int ir = c0 + ty + j * 8;
        int ic = r0 + tx;
        t[ty + j * 8][tx] = (ir < R && ic < C) ? in[(size_t)ir * C + ic] : 0.0f;
    }
    __syncthreads();
#pragma unroll
    for (int j = 0; j < 4; ++j)
        out[(size_t)(r0 + ty + j * 8) * outC + c0 + tx] = f2b(t[tx][ty + j * 8]);
}

// ---------------------------------------------------------------------------
// RMSNorm (standalone, for x2 -> h2b)
// ---------------------------------------------------------------------------
__global__ __launch_bounds__(256)
void rmsnorm_k(const float* __restrict__ x, const float* __restrict__ w,
               u16* __restrict__ out) {
    const int row = blockIdx.x;
    const int tid = threadIdx.x;
    const float4 v = ((const float4*)(x + (size_t)row * D_MODEL))[tid];
    float ss = v.x * v.x + v.y * v.y + v.z * v.z + v.w * v.w;
    for (int o = 32; o; o >>= 1) ss += __shfl_down(ss, o);
    __shared__ float red[4];
    if ((tid & 63) == 0) red[tid >> 6] = ss;
    __syncthreads();
    const float tot = red[0] + red[1] + red[2] + red[3];
    const float rs = rsqrtf(tot * (1.0f / D_MODEL) + 1e-6f);
    const float4 wv = ((const float4*)w)[tid];
    u16* op = out + (size_t)row * D_MODEL + tid * 4;
    u32 p0 = (u32)f2b(v.x * rs * wv.x) | ((u32)f2b(v.y * rs * wv.y) << 16);
    u32 p1 = (u32)f2b(v.z * rs * wv.z) | ((u32)f2b(v.w * rs * wv.w) << 16);
    uint2 pk; pk.x = p0; pk.y = p1;
    *(uint2*)op = pk;
}

// ---------------------------------------------------------------------------
// Pack K/V per head, K-RoPE fused:
//   kp[h][s][d] = rope(qkv[s][1024 + h*64 + d])
//   vt[h][d][s] = qkv[s][2048 + h*64 + d]
// ---------------------------------------------------------------------------
__global__ __launch_bounds__(256)
void packkv_k(const u16* __restrict__ qkv, const float* __restrict__ fc,
              const float* __restrict__ fs, u16* __restrict__ vt,
              u16* __restrict__ kp) {
    __shared__ u16 t[32][33];
    const int h = blockIdx.z;
    const int t0 = blockIdx.x * 32;
    const int d0 = blockIdx.y * 32;
    const int tx = threadIdx.x, ty = threadIdx.y;
#pragma unroll
    for (int j = 0; j < 4; ++j)
        t[ty + j * 8][tx] =
            qkv[(size_t)(t0 + ty + j * 8) * QKV_LD + 2 * D_MODEL + h * DK + d0 + tx];

    const int id = ty * 32 + tx;
    const int sA = t0 + (id >> 3);
    const int dA = d0 + (id & 7) * 4;
    uint2 kvp = *(const uint2*)(qkv + (size_t)sA * QKV_LD + D_MODEL + h * DK + dA);
    const int fi = sA * 32 + (dA >> 1);
    const float cc0 = fc[fi], ss0 = fs[fi];
    const float cc1 = fc[fi + 1], ss1 = fs[fi + 1];
    auto rpk = [](u32 w, float c, float s) -> u32 {
        const float a = b2f((u16)w), b = b2f((u16)(w >> 16));
        return (u32)f2b(a * c - b * s) | ((u32)f2b(a * s + b * c) << 16);
    };
    kvp.x = rpk(kvp.x, cc0, ss0);
    kvp.y = rpk(kvp.y, cc1, ss1);
    *(uint2*)(kp + ((size_t)h * S_LEN + sA) * DK + dA) = kvp;

    __syncthreads();
#pragma unroll
    for (int j = 0; j < 4; ++j)
        vt[(size_t)h * DK * S_LEN + (size_t)(d0 + ty + j * 8) * S_LEN + t0 + tx] =
            t[tx][ty + j * 8];
}

// ---------------------------------------------------------------------------
// 128x128 GEMM, BK=64 + XOR-swizzled staging (verified round 6).
// ---------------------------------------------------------------------------
template <int EPI>
__global__ __launch_bounds__(256)
void gemm128(const u16* __restrict__ A, int lda, const u16* __restrict__ Bt, int ldb,
             void* __restrict__ C, int ldc, int K, const float* __restrict__ resid) {
    const int m0 = blockIdx.y * 128, n0 = blockIdx.x * 128;
    const int tid = threadIdx.x;
    const int wave = tid >> 6, lane = tid & 63;
    const int wr = wave >> 1, wc = wave & 1;
    const int r16 = lane & 15, kq = lane >> 4;

    __shared__ __align__(16) u16 As[128 * 64];
    __shared__ __align__(16) u16 Bs[128 * 64];

    const int srow = tid >> 3;                       // 0..31
    const int scol = ((tid & 7) ^ (srow & 7)) * 8;   // pre-swizzled source col
    const u16* ag0 = A + (size_t)(m0 +  0 + srow) * lda + scol;
    const u16* ag1 = A + (size_t)(m0 + 32 + srow) * lda + scol;
    const u16* ag2 = A + (size_t)(m0 + 64 + srow) * lda + scol;
    const u16* ag3 = A + (size_t)(m0 + 96 + srow) * lda + scol;
    const u16* bg0 = Bt + (size_t)(n0 +  0 + srow) * ldb + scol;
    const u16* bg1 = Bt + (size_t)(n0 + 32 + srow) * ldb + scol;
    const u16* bg2 = Bt + (size_t)(n0 + 64 + srow) * ldb + scol;
    const u16* bg3 = Bt + (size_t)(n0 + 96 + srow) * ldb + scol;
    u16* const ad = As + tid * 8;
    u16* const bd = Bs + tid * 8;

    f32x4 acc[16];
#pragma unroll
    for (int i = 0; i < 16; ++i) acc[i] = f32x4{0.f, 0.f, 0.f, 0.f};

    const int rsw = r16 & 7;
    for (int k0 = 0; k0 < K; k0 += 64) {
        __syncthreads();
        gll16(ag0 + k0, ad);
        gll16(ag1 + k0, ad + 2048);
        gll16(ag2 + k0, ad + 4096);
        gll16(ag3 + k0, ad + 6144);
        gll16(bg0 + k0, bd);
        gll16(bg1 + k0, bd + 2048);
        gll16(bg2 + k0, bd + 4096);
        gll16(bg3 + k0, bd + 6144);
        __syncthreads();
#pragma unroll
        for (int ks = 0; ks < 2; ++ks) {
            const int slot = (((ks << 2) | kq) ^ rsw) * 8;
            bf16x8 af[4], bf[4];
#pragma unroll
            for (int mt = 0; mt < 4; ++mt)
                af[mt] = *(const bf16x8*)&As[(wr * 64 + mt * 16 + r16) * 64 + slot];
#pragma unroll
            for (int nt = 0; nt < 4; ++nt)
                bf[nt] = *(const bf16x8*)&Bs[(wc * 64 + nt * 16 + r16) * 64 + slot];
#pragma unroll
            for (int mt = 0; mt < 4; ++mt)
#pragma unroll
                for (int nt = 0; nt < 4; ++nt)
                    acc[mt * 4 + nt] = MFMA16(af[mt], bf[nt], acc[mt * 4 + nt], 0, 0, 0);
        }
    }

#pragma unroll
    for (int mt = 0; mt < 4; ++mt) {
#pragma unroll
        for (int nt = 0; nt < 4; ++nt) {
            const int col = n0 + wc * 64 + nt * 16 + r16;
#pragma unroll
            for (int j = 0; j < 4; ++j) {
                const int row = m0 + wr * 64 + mt * 16 + kq * 4 + j;
                if (EPI == 0) {
                    ((u16*)C)[(size_t)row * ldc + col] = f2b(acc[mt * 4 + nt][j]);
                } else {
                    ((float*)C)[(size_t)row * ldc + col] =
                        resid[(size_t)row * ldc + col] + acc[mt * 4 + nt][j];
                }
            }
        }
    }
}

// ---------------------------------------------------------------------------
// 128(M) x 64(N) GEMM + fp32 residual epilogue, BK=64 + XOR-swizzle
// (verified round 6). LDS = 16 + 8 = 24 KB.
// ---------------------------------------------------------------------------
__global__ __launch_bounds__(256)
void gemm64r(const u16* __restrict__ A, int lda, const u16* __restrict__ Bt, int ldb,
             float* __restrict__ C, int ldc, int K, const float* __restrict__ resid) {
    const int m0 = blockIdx.y * 128, n0 = blockIdx.x * 64;
    const int tid = threadIdx.x;
    const int wave = tid >> 6, lane = tid & 63;
    const int r16 = lane & 15, kq = lane >> 4;

    __shared__ __align__(16) u16 As[128 * 64];
    __shared__ __align__(16) u16 Bs[64 * 64];

    const int srow = tid >> 3;
    const int scol = ((tid & 7) ^ (srow & 7)) * 8;
    const u16* ag0 = A + (size_t)(m0 +  0 + srow) * lda + scol;
    const u16* ag1 = A + (size_t)(m0 + 32 + srow) * lda + scol;
    const u16* ag2 = A + (size_t)(m0 + 64 + srow) * lda + scol;
    const u16* ag3 = A + (size_t)(m0 + 96 + srow) * lda + scol;
    const u16* bg0 = Bt + (size_t)(n0 +  0 + srow) * ldb + scol;
    const u16* bg1 = Bt + (size_t)(n0 + 32 + srow) * ldb + scol;
    u16* const ad = As + tid * 8;
    u16* const bd = Bs + tid * 8;

    f32x4 acc[8];
#pragma unroll
    for (int i = 0; i < 8; ++i) acc[i] = f32x4{0.f, 0.f, 0.f, 0.f};

    const int rsw = r16 & 7;
    for (int k0 = 0; k0 < K; k0 += 64) {
        __syncthreads();
        gll16(ag0 + k0, ad);
        gll16(ag1 + k0, ad + 2048);
        gll16(ag2 + k0, ad + 4096);
        gll16(ag3 + k0, ad + 6144);
        gll16(bg0 + k0, bd);
        gll16(bg1 + k0, bd + 2048);
        __syncthreads();
#pragma unroll
        for (int ks = 0; ks < 2; ++ks) {
            const int slot = (((ks << 2) | kq) ^ rsw) * 8;
            bf16x8 af[2], bf[4];
#pragma unroll
            for (int mt = 0; mt < 2; ++mt)
                af[mt] = *(const bf16x8*)&As[(wave * 32 + mt * 16 + r16) * 64 + slot];
#pragma unroll
            for (int nt = 0; nt < 4; ++nt)
                bf[nt] = *(const bf16x8*)&Bs[(nt * 16 + r16) * 64 + slot];
#pragma unroll
            for (int mt = 0; mt < 2; ++mt)
#pragma unroll
                for (int nt = 0; nt < 4; ++nt)
                    acc[mt * 4 + nt] = MFMA16(af[mt], bf[nt], acc[mt * 4 + nt], 0, 0, 0);
        }
    }

#pragma unroll
    for (int mt = 0; mt < 2; ++mt)
#pragma unroll
        for (int nt = 0; nt < 4; ++nt) {
            const int col = n0 + nt * 16 + r16;
#pragma unroll
            for (int j = 0; j < 4; ++j) {
                const int row = m0 + wave * 32 + mt * 16 + kq * 4 + j;
                C[(size_t)row * ldc + col] =
                    resid[(size_t)row * ldc + col] + acc[mt * 4 + nt][j];
            }
        }
}

// ---------------------------------------------------------------------------
// FFN dual GEMM v3: tile 128(M) x 96(N per matrix), BK=64 (verified win).
// ---------------------------------------------------------------------------
__global__ __launch_bounds__(256, 3)
void gemm_dual96x(const u16* __restrict__ A, int lda,
                  const u16* __restrict__ B1, const u16* __restrict__ B3, int ldb,
                  u16* __restrict__ C, int ldc, int K) {
    const int m0 = blockIdx.y * 128, n0 = blockIdx.x * 96;
    const int tid = threadIdx.x;
    const int wave = tid >> 6, lane = tid & 63;
    const int wr = wave >> 1, wc = wave & 1;
    const int r16 = lane & 15, kq = lane >> 4;

    __shared__ __align__(16) u16 As[128 * 64];   // swizzled rows
    __shared__ __align__(16) u16 Bs[192 * 64];   // rows 0-95 = B1, 96-191 = B3

    const int srow = tid >> 3;                       // 0..31 (row within call)
    const int scol = ((tid & 7) ^ (srow & 7)) * 8;   // pre-swizzled source col
    const u16* ag0 = A + (size_t)(m0 +  0 + srow) * lda + scol;
    const u16* ag1 = A + (size_t)(m0 + 32 + srow) * lda + scol;
    const u16* ag2 = A + (size_t)(m0 + 64 + srow) * lda + scol;
    const u16* ag3 = A + (size_t)(m0 + 96 + srow) * lda + scol;
    const u16* bg0 = B1 + (size_t)(n0 +  0 + srow) * ldb + scol;
    const u16* bg1 = B1 + (size_t)(n0 + 32 + srow) * ldb + scol;
    const u16* bg2 = B1 + (size_t)(n0 + 64 + srow) * ldb + scol;
    const u16* bg3 = B3 + (size_t)(n0 +  0 + srow) * ldb + scol;
    const u16* bg4 = B3 + (size_t)(n0 + 32 + srow) * ldb + scol;
    const u16* bg5 = B3 + (size_t)(n0 + 64 + srow) * ldb + scol;
    u16* const ad = As + tid * 8;
    u16* const bd = Bs + tid * 8;

    f32x4 acc1[12], acc3[12];
#pragma unroll
    for (int i = 0; i < 12; ++i) {
        acc1[i] = f32x4{0.f, 0.f, 0.f, 0.f};
        acc3[i] = f32x4{0.f, 0.f, 0.f, 0.f};
    }

    const int rsw = r16 & 7;
    for (int k0 = 0; k0 < K; k0 += 64) {
        __syncthreads();
        gll16(ag0 + k0, ad);
        gll16(ag1 + k0, ad + 2048);
        gll16(ag2 + k0, ad + 4096);
        gll16(ag3 + k0, ad + 6144);
        gll16(bg0 + k0, bd);
        gll16(bg1 + k0, bd + 2048);
        gll16(bg2 + k0, bd + 4096);
        gll16(bg3 + k0, bd + 6144);
        gll16(bg4 + k0, bd + 8192);
        gll16(bg5 + k0, bd + 10240);
        __syncthreads();
#pragma unroll
        for (int ks = 0; ks < 2; ++ks) {
            const int slot = (((ks << 2) | kq) ^ rsw) * 8;
            bf16x8 af[4], b1f[3], b3f[3];
#pragma unroll
            for (int mt = 0; mt < 4; ++mt)
                af[mt] = *(const bf16x8*)&As[(wr * 64 + mt * 16 + r16) * 64 + slot];
#pragma unroll
            for (int nt = 0; nt < 3; ++nt) {
                b1f[nt] = *(const bf16x8*)&Bs[(wc * 48 + nt * 16 + r16) * 64 + slot];
                b3f[nt] = *(const bf16x8*)&Bs[(96 + wc * 48 + nt * 16 + r16) * 64 + slot];
            }
#pragma unroll
            for (int mt = 0; mt < 4; ++mt)
#pragma unroll
                for (int nt = 0; nt < 3; ++nt) {
                    acc1[mt * 3 + nt] = MFMA16(af[mt], b1f[nt], acc1[mt * 3 + nt], 0, 0, 0);
                    acc3[mt * 3 + nt] = MFMA16(af[mt], b3f[nt], acc3[mt * 3 + nt], 0, 0, 0);
                }
        }
    }

#pragma unroll
    for (int mt = 0; mt < 4; ++mt)
#pragma unroll
        for (int nt = 0; nt < 3; ++nt) {
            const int col = n0 + wc * 48 + nt * 16 + r16;
#pragma unroll
            for (int j = 0; j < 4; ++j) {
                const int row = m0 + wr * 64 + mt * 16 + kq * 4 + j;
                const float v1 = acc1[mt * 3 + nt][j];
                const float v3 = acc3[mt * 3 + nt][j];
                const float sig = 1.0f / (1.0f + __expf(-v1));
                C[(size_t)row * ldc + col] = f2b(v1 * sig * v3);
            }
        }
}

// ---------------------------------------------------------------------------
// Flash attention v11: v10 (causal pairing, KVBLK=128) + FUSED dual-q tile.
// LDS-pipe arithmetic: per tilec a lane reads 128B K + 128B V + 64B Ps
// round-trip -> ~40us of the 70us wall is DS-pipe serialization. In the
// paired region (t <= qa, ~33 of 65 tiles) the A- and B-tilec read
// IDENTICAL K/V fragments; tile_dual loads each fragment ONCE and feeds
// both q-tiles' MFMAs -> LDS read traffic -27% overall. Ps splits into two
// regions (both live in a fused tile). LDS = 2*16(K) + 2*16(V) + 2*8(Ps)
// = 80 KB -> still 2 blocks/CU (160 KB).
// ---------------------------------------------------------------------------
__global__ __launch_bounds__(256)
void flash_k(const u16* __restrict__ qkv, const u16* __restrict__ vt,
             const u16* __restrict__ kp, const float* __restrict__ fc,
             const float* __restrict__ fs, u16* __restrict__ ctx) {
    const int h = blockIdx.x;
    const int pair = blockIdx.y;       // 0..31
    const int qa = pair, qb = 63 - pair;
    const int tid = threadIdx.x;
    const int wave = tid >> 6, lane = tid & 63;
    const int r16 = lane & 15, kq = lane >> 4;

    __shared__ __align__(16) u16 Kb[2][2 * 64 * 64];   // [buf][sub 64-tile]
    __shared__ __align__(16) u16 Vb[2][2 * 64 * 64];
    __shared__ __align__(16) u16 PsB[4 * 16 * 64];     // per-wave [q][kv]
    __shared__ __align__(16) u16 PsA[4 * 16 * 64];

    const u16* kb = kp + (size_t)h * S_LEN * DK;
    const u16* vb = vt + (size_t)h * DK * S_LEN;
    const int srow = tid >> 3;
    const int lcol = ((tid & 7) ^ (srow & 7)) * 8;
    const int qloc = wave * 16 + r16;
    const int sw = r16 & 7;
    const int c0 = (kq ^ sw) * 8;
    const int c1 = ((4 ^ kq) ^ sw) * 8;
    const int psw = r16 & 14;
    u16* psB = PsB + wave * 1024 + r16 * 64;
    u16* psA = PsA + wave * 1024 + r16 * 64;

    const float SC = 0.125f * 1.44269504f;
    auto rp = [SC](u32 w, float c, float s) -> u32 {
        const float a = b2f((u16)w), b = b2f((u16)(w >> 16));
        return (u32)f2b((a * c - b * s) * SC) |
               ((u32)f2b((a * s + b * c) * SC) << 16);
    };
    // Q: raw load + RoPE + scale, in registers (for both q-tiles)
    auto loadq = [&](int qglob, bf16x8& q0out, bf16x8& q1out) {
        const u16* qrow = qkv + (size_t)qglob * QKV_LD + h * DK;
        uint4 uq0 = *(const uint4*)(qrow + kq * 8);
        uint4 uq1 = *(const uint4*)(qrow + 32 + kq * 8);
        const float4 c0v = *(const float4*)(fc + qglob * 32 + kq * 4);
        const float4 s0v = *(const float4*)(fs + qglob * 32 + kq * 4);
        const float4 c1v = *(const float4*)(fc + qglob * 32 + 16 + kq * 4);
        const float4 s1v = *(const float4*)(fs + qglob * 32 + 16 + kq * 4);
        uq0.x = rp(uq0.x, c0v.x, s0v.x); uq0.y = rp(uq0.y, c0v.y, s0v.y);
        uq0.z = rp(uq0.z, c0v.z, s0v.z); uq0.w = rp(uq0.w, c0v.w, s0v.w);
        uq1.x = rp(uq1.x, c1v.x, s1v.x); uq1.y = rp(uq1.y, c1v.y, s1v.y);
        uq1.z = rp(uq1.z, c1v.z, s1v.z); uq1.w = rp(uq1.w, c1v.w, s1v.w);
        q0out = __builtin_bit_cast(bf16x8, uq0);
        q1out = __builtin_bit_cast(bf16x8, uq1);
    };
    const int qgA = qa * 64 + qloc;
    const int qgB = qb * 64 + qloc;
    bf16x8 qfA0, qfA1, qfB0, qfB1;
    loadq(qgA, qfA0, qfA1);
    loadq(qgB, qfB0, qfB1);

    f32x4 oA[4], oB[4];
#pragma unroll
    for (int i = 0; i < 4; ++i) {
        oA[i] = f32x4{0.f, 0.f, 0.f, 0.f};
        oB[i] = f32x4{0.f, 0.f, 0.f, 0.f};
    }
    f32x4 laccA = f32x4{0.f, 0.f, 0.f, 0.f};
    f32x4 laccB = f32x4{0.f, 0.f, 0.f, 0.f};
    const uint4 uone = make_uint4(0x3F803F80u, 0x3F803F80u, 0x3F803F80u, 0x3F803F80u);
    const bf16x8 ones = __builtin_bit_cast(bf16x8, uone);

    // single-q tile (B only): S^T = K.Q^T -> p=2^s -> packed P^T -> PV
    auto tile_single = [&](const u16* Ks, const u16* Vs, bool dmask) {
        f32x4 s[4];
#pragma unroll
        for (int nt = 0; nt < 4; ++nt) {
            s[nt] = f32x4{0.f, 0.f, 0.f, 0.f};
            const bf16x8 k0 = *(const bf16x8*)&Ks[(nt * 16 + r16) * 64 + c0];
            s[nt] = MFMA16(k0, qfB0, s[nt], 0, 0, 0);
            const bf16x8 k1 = *(const bf16x8*)&Ks[(nt * 16 + r16) * 64 + c1];
            s[nt] = MFMA16(k1, qfB1, s[nt], 0, 0, 0);
        }
        float pr[16];
#pragma unroll
        for (int nt = 0; nt < 4; ++nt)
#pragma unroll
            for (int j = 0; j < 4; ++j) pr[nt * 4 + j] = EXP2(s[nt][j]);
        if (dmask) {
#pragma unroll
            for (int nt = 0; nt < 4; ++nt)
#pragma unroll
                for (int j = 0; j < 4; ++j)
                    if ((nt * 16 + kq * 4 + j) > qloc) pr[nt * 4 + j] = 0.f;
        }
#pragma unroll
        for (int nt = 0; nt < 4; ++nt) {
            uint2 pk;
            pk.x = pk_trunc(pr[nt * 4 + 0], pr[nt * 4 + 1]);
            pk.y = pk_trunc(pr[nt * 4 + 2], pr[nt * 4 + 3]);
            *(uint2*)&psB[((nt * 4 + kq) ^ psw) * 4] = pk;
        }
#pragma unroll
        for (int ks = 0; ks < 2; ++ks) {
            const bf16x8 pf = *(const bf16x8*)&psB[((8 * ks + 2 * kq) ^ psw) * 4];
            laccB = MFMA16(ones, pf, laccB, 0, 0, 0);
            const int cv = (((ks << 2) ^ kq) ^ sw) * 8;
#pragma unroll
            for (int nt = 0; nt < 4; ++nt) {
                const bf16x8 vf = *(const bf16x8*)&Vs[(nt * 16 + r16) * 64 + cv];
                oB[nt] = MFMA16(vf, pf, oB[nt], 0, 0, 0);
            }
        }
    };

    // fused dual-q tile: each K/V fragment loaded ONCE, feeds both q-tiles.
    // B is never diag-masked here (t <= qa < qb); A masked when t == qa.
    auto tile_dual = [&](const u16* Ks, const u16* Vs, bool maskA) {
        f32x4 sB[4], sA[4];
#pragma unroll
        for (int nt = 0; nt < 4; ++nt) {
            sB[nt] = f32x4{0.f, 0.f, 0.f, 0.f};
            sA[nt] = f32x4{0.f, 0.f, 0.f, 0.f};
            const bf16x8 k0 = *(const bf16x8*)&Ks[(nt * 16 + r16) * 64 + c0];
            sB[nt] = MFMA16(k0, qfB0, sB[nt], 0, 0, 0);
            sA[nt] = MFMA16(k0, qfA0, sA[nt], 0, 0, 0);
            const bf16x8 k1 = *(const bf16x8*)&Ks[(nt * 16 + r16) * 64 + c1];
            sB[nt] = MFMA16(k1, qfB1, sB[nt], 0, 0, 0);
            sA[nt] = MFMA16(k1, qfA1, sA[nt], 0, 0, 0);
        }
        float prB[16], prA[16];
#pragma unroll
        for (int nt = 0; nt < 4; ++nt)
#pragma unroll
            for (int j = 0; j < 4; ++j) {
                prB[nt * 4 + j] = EXP2(sB[nt][j]);
                prA[nt * 4 + j] = EXP2(sA[nt][j]);
            }
        if (maskA) {
#pragma unroll
            for (int nt = 0; nt < 4; ++nt)
#pragma unroll
                for (int j = 0; j < 4; ++j)
                    if ((nt * 16 + kq * 4 + j) > qloc) prA[nt * 4 + j] = 0.f;
        }
#pragma unroll
        for (int nt = 0; nt < 4; ++nt) {
            uint2 pkB, pkA;
            pkB.x = pk_trunc(prB[nt * 4 + 0], prB[nt * 4 + 1]);
            pkB.y = pk_trunc(prB[nt * 4 + 2], prB[nt * 4 + 3]);
            pkA.x = pk_trunc(prA[nt * 4 + 0], prA[nt * 4 + 1]);
            pkA.y = pk_trunc(prA[nt * 4 + 2], prA[nt * 4 + 3]);
            *(uint2*)&psB[((nt * 4 + kq) ^ psw) * 4] = pkB;
            *(uint2*)&psA[((nt * 4 + kq) ^ psw) * 4] = pkA;
        }
#pragma unroll
        for (int ks = 0; ks < 2; ++ks) {
            const bf16x8 pfB = *(const bf16x8*)&psB[((8 * ks + 2 * kq) ^ psw) * 4];
            const bf16x8 pfA = *(const bf16x8*)&psA[((8 * ks + 2 * kq) ^ psw) * 4];
            laccB = MFMA16(ones, pfB, laccB, 0, 0, 0);
            laccA = MFMA16(ones, pfA, laccA, 0, 0, 0);
            const int cv = (((ks << 2) ^ kq) ^ sw) * 8;
#pragma unroll
            for (int nt = 0; nt < 4; ++nt) {
                const bf16x8 vf = *(const bf16x8*)&Vs[(nt * 16 + r16) * 64 + cv];
                oB[nt] = MFMA16(vf, pfB, oB[nt], 0, 0, 0);
                oA[nt] = MFMA16(vf, pfA, oA[nt], 0, 0, 0);
            }
        }
    };

    // stage one 64-kv tile t into (kd, vd) -- identical pattern to v10
    auto stage = [&](int t, u16* kd, u16* vd) {
        const int tb = t * 64;
#pragma unroll
        for (int i = 0; i < 2; ++i) {
            const int r = srow + i * 32;
            gll16(kb + (size_t)(tb + r) * DK + lcol, kd + tid * 8 + i * 2048);
            gll16(vb + (size_t)r * S_LEN + tb + lcol, vd + tid * 8 + i * 2048);
        }
    };

    // preload tiles 0,1 into buffer 0 (qb >= 32, so tile 1 always exists)
    stage(0, Kb[0], Vb[0]);
    stage(1, Kb[0] + 4096, Vb[0] + 4096);

    const int nT = (qb + 2) >> 1;      // ceil((qb+1)/2) iterations
    for (int T = 0; T < nT; ++T) {
        __syncthreads();   // drains this iteration's buffer; prev buffer free
        const int nb = (T + 1) * 2;
        if (nb <= qb) {    // prefetch tiles nb, nb+1 into the other buffer
            u16* kd = ((T + 1) & 1) ? Kb[1] : Kb[0];
            u16* vd = ((T + 1) & 1) ? Vb[1] : Vb[0];
            stage(nb, kd, vd);
            if (nb + 1 <= qb) stage(nb + 1, kd + 4096, vd + 4096);
        }
        const u16* Ks = (T & 1) ? Kb[1] : Kb[0];
        const u16* Vs = (T & 1) ? Vb[1] : Vb[0];

        // subtile 0: t = 2T (always <= qb since T < nT)
        {
            const int t = 2 * T;
            if (t <= qa) tile_dual(Ks, Vs, t == qa);
            else         tile_single(Ks, Vs, t == qb);
        }
        // subtile 1: t = 2T+1 (may exceed qb on the last iteration)
        if (2 * T + 1 <= qb) {
            const int t = 2 * T + 1;
            if (t <= qa) tile_dual(Ks + 4096, Vs + 4096, t == qa);
            else         tile_single(Ks + 4096, Vs + 4096, t == qb);
        }
    }

    // l: every lacc element equals the full sum for column q=r16
    auto wout = [&](f32x4 (&o)[4], float lsum, int qg) {
        const float inv = 1.0f / lsum;
        const size_t row = qg;
#pragma unroll
        for (int nt = 0; nt < 4; ++nt) {
            uint2 pk;
            pk.x = (u32)f2b(o[nt][0] * inv) | ((u32)f2b(o[nt][1] * inv) << 16);
            pk.y = (u32)f2b(o[nt][2] * inv) | ((u32)f2b(o[nt][3] * inv) << 16);
            *(uint2*)&ctx[row * D_MODEL + h * DK + nt * 16 + kq * 4] = pk;
        }
    };
    wout(oA, laccA[0], qgA);
    wout(oB, laccB[0], qgB);
}

// ---------------------------------------------------------------------------
extern "C" void kernel_launch(void* const* d_in, const int* in_sizes, int n_in,
                              void* d_out, int out_size, void* d_ws, size_t ws_size,
                              hipStream_t stream) {
    const float* x    = (const float*)d_in[0];
    const float* fcos = (const float*)d_in[1];
    const float* fsin = (const float*)d_in[2];
    const float* Wq = (const float*)d_in[4];
    const float* Wk = (const float*)d_in[5];
    const float* Wv = (const float*)d_in[6];
    const float* Wo = (const float*)d_in[7];
    const float* ln1 = (const float*)d_in[8];
    const float* ln2 = (const float*)d_in[9];
    const float* w1 = (const float*)d_in[10];
    const float* w2 = (const float*)d_in[11];
    const float* w3 = (const float*)d_in[12];
    float* out = (float*)d_out;

    char* ws = (char*)d_ws;
    size_t off = 0;
    auto alloc = [&](size_t bytes) -> char* {
        char* p = ws + off;
        off += (bytes + 255) & ~(size_t)255;
        return p;
    };
    u16* hb    = (u16*)alloc((size_t)S_LEN * D_MODEL * 2);
    u16* wqkvt = (u16*)alloc((size_t)QKV_LD * D_MODEL * 2);  // [3072][1024]
    u16* wot   = (u16*)alloc((size_t)D_MODEL * D_MODEL * 2);
    u16* qkvb  = (u16*)alloc((size_t)S_LEN * QKV_LD * 2);    // [4096][3072]
    u16* vt    = (u16*)alloc((size_t)S_LEN * D_MODEL * 2);   // [H][DK][S]
    u16* kpack = (u16*)alloc((size_t)S_LEN * D_MODEL * 2);   // [H][S][DK]
    u16* ctxb  = (u16*)alloc((size_t)S_LEN * D_MODEL * 2);
    float* x2  = (float*)alloc((size_t)S_LEN * D_MODEL * 4);
    u16* h2b   = (u16*)alloc((size_t)S_LEN * D_MODEL * 2);
    u16* w1t   = (u16*)alloc((size_t)HIDP * D_MODEL * 2);    // [2880][1024]
    u16* w3t   = (u16*)alloc((size_t)HIDP * D_MODEL * 2);
    u16* w2t   = (u16*)alloc((size_t)D_MODEL * HIDP * 2);    // [1024][2880]
    u16* ffb   = (u16*)alloc((size_t)S_LEN * HIDP * 2);      // [4096][2880]

    const dim3 tb32(32, 8);

    // weight transposes + rmsnorm(x, ln1), one launch
    prep_k<<<16832, 256, 0, stream>>>(
        Wq, Wk, Wv, Wo, w1, w3, w2,
        wqkvt, wqkvt + (size_t)D_MODEL * D_MODEL,
        wqkvt + (size_t)2 * D_MODEL * D_MODEL, wot, w1t, w3t, w2t,
        x, ln1, hb);

    // QKV = h @ [Wq|Wk|Wv]   (one 4096x3072x1024 GEMM, raw Q/K)
    gemm128<0><<<dim3(QKV_LD / 128, S_LEN / 128), 256, 0, stream>>>(
        hb, D_MODEL, wqkvt, D_MODEL, qkvb, QKV_LD, D_MODEL, nullptr);

    // K packed (+RoPE) + V transposed per head
    packkv_k<<<dim3(S_LEN / 32, DK / 32, NHEAD), tb32, 0, stream>>>(
        qkvb, fcos, fsin, vt, kpack);

    // flash attention (Q RoPE fused; causal pairing, KVBLK=128, fused dual-q)
    flash_k<<<dim3(NHEAD, 32), 256, 0, stream>>>(qkvb, vt, kpack, fcos, fsin, ctxb);

    // x2 = x + ctx @ Wo
    gemm64r<<<dim3(D_MODEL / 64, S_LEN / 128), 256, 0, stream>>>(
        ctxb, D_MODEL, wot, D_MODEL, x2, D_MODEL, D_MODEL, x);

    // h2 = rmsnorm(x2, ln2)
    rmsnorm_k<<<S_LEN, 256, 0, stream>>>(x2, ln2, h2b);

    // ff = silu(h2@w1) * (h2@w3)
    gemm_dual96x<<<dim3(HIDP / 96, S_LEN / 128), 256, 0, stream>>>(
        h2b, D_MODEL, w1t, w3t, D_MODEL, ffb, HIDP, D_MODEL);

    // out = x2 + ff @ w2
    gemm64r<<<dim3(D_MODEL / 64, S_LEN / 128), 256, 0, stream>>>(
        ffb, HIDP, w2t, HIDP, out, D_MODEL, HIDP, x2);
}

// Round 9
// 383.085 us; speedup vs baseline: 1.0050x; 1.0050x over previous
//
#include <hip/hip_runtime.h>

#define S_LEN 4096
#define D_MODEL 1024
#define NHEAD 16
#define DK 64
#define HID 2730
#define HIDP 2880
#define QKV_LD 3072

typedef unsigned short u16;
typedef unsigned int u32;
typedef __bf16 bf16x8 __attribute__((ext_vector_type(8)));
typedef float f32x4 __attribute__((ext_vector_type(4)));

#define MFMA16 __builtin_amdgcn_mfma_f32_16x16x32_bf16
// raw v_exp_f32 (2^x): scores bounded (|s| < ~30), no OCML guard code needed
#define EXP2 __builtin_amdgcn_exp2f

__device__ __forceinline__ float b2f(u16 u) {
    return __builtin_bit_cast(float, (u32)u << 16);
}
__device__ __forceinline__ u16 f2b(float f) {
    u32 u = __builtin_bit_cast(u32, f);
    u += 0x7FFF + ((u >> 16) & 1);
    return (u16)(u >> 16);
}
// pack two f32 -> two bf16 (truncate) in one v_perm_b32
__device__ __forceinline__ u32 pk_trunc(float lo, float hi) {
    return __builtin_amdgcn_perm(__builtin_bit_cast(u32, hi),
                                 __builtin_bit_cast(u32, lo), 0x07060302u);
}
// async global->LDS, 16B per lane; dest must be wave-uniform base + lane*16
__device__ __forceinline__ void gll16(const u16* g, u16* l) {
    __builtin_amdgcn_global_load_lds(
        (__attribute__((address_space(1))) void*)(g),
        (__attribute__((address_space(3))) void*)(l),
        16, 0, 0);
}

// ---------------------------------------------------------------------------
// Prep: 7 weight transposes (fp32->bf16, zero-pad) + rmsnorm(x, ln1) in ONE
// launch. Flat grid, 256-thread blocks. Blocks 0..12735 = tcast segments;
// blocks 12736..16831 = rmsnorm rows.  (HIDP = 2880 = 30*96)
// ---------------------------------------------------------------------------
__global__ __launch_bounds__(256)
void prep_k(const float* s0, const float* s1, const float* s2,
            const float* s3, const float* s4, const float* s5,
            const float* s6, u16* d0, u16* d1, u16* d2, u16* d3,
            u16* d4, u16* d5, u16* d6,
            const float* __restrict__ x, const float* __restrict__ ln1,
            u16* __restrict__ hb) {
    __shared__ float t[32][33];
    __shared__ float red[4];
    const int bid = blockIdx.x;
    const int tid = threadIdx.x;

    if (bid >= 12736) {   // ---- rmsnorm path ----
        const int row = bid - 12736;
        const float4 v = ((const float4*)(x + (size_t)row * D_MODEL))[tid];
        float ss = v.x * v.x + v.y * v.y + v.z * v.z + v.w * v.w;
        for (int o = 32; o; o >>= 1) ss += __shfl_down(ss, o);
        if ((tid & 63) == 0) red[tid >> 6] = ss;
        __syncthreads();
        const float tot = red[0] + red[1] + red[2] + red[3];
        const float rs = rsqrtf(tot * (1.0f / D_MODEL) + 1e-6f);
        const float4 wv = ((const float4*)ln1)[tid];
        u16* op = hb + (size_t)row * D_MODEL + tid * 4;
        u32 p0 = (u32)f2b(v.x * rs * wv.x) | ((u32)f2b(v.y * rs * wv.y) << 16);
        u32 p1 = (u32)f2b(v.z * rs * wv.z) | ((u32)f2b(v.w * rs * wv.w) << 16);
        uint2 pk; pk.x = p0; pk.y = p1;
        *(uint2*)op = pk;
        return;
    }

    // ---- transpose path ----
    const float* srcs[7] = {s0, s1, s2, s3, s4, s5, s6};
    u16* dsts[7] = {d0, d1, d2, d3, d4, d5, d6};
    const int RR[7] = {1024, 1024, 1024, 1024, 1024, 1024, 2730};
    const int CC[7] = {1024, 1024, 1024, 1024, 2730, 2730, 1024};
    const int OC[7] = {1024, 1024, 1024, 1024, 1024, 1024, 2880};
    const int XD[7] = {32, 32, 32, 32, 32, 32, 90};

    int seg, start;
    if (bid < 4096)      { seg = bid >> 10; start = seg << 10; }
    else if (bid < 6976) { seg = 4; start = 4096; }
    else if (bid < 9856) { seg = 5; start = 6976; }
    else                 { seg = 6; start = 9856; }
    const int local = bid - start;
    const int bx = local % XD[seg], byy = local / XD[seg];
    const float* in = srcs[seg];
    u16* out = dsts[seg];
    const int R = RR[seg], C = CC[seg], outC = OC[seg];

    const int r0 = byy * 32;
    const int c0 = bx * 32;
    const int tx = tid & 31, ty = tid >> 5;
#pragma unroll
    for (int j = 0; j < 4; ++j) {
        int ir = c0 + ty + j * 8;
        int ic = r0 + tx;
        t[ty + j * 8][tx] = (ir < R && ic < C) ? in[(size_t)ir * C + ic] : 0.0f;
    }
    __syncthreads();
#pragma unroll
    for (int j = 0; j < 4; ++j)
        out[(size_t)(r0 + ty + j * 8) * outC + c0 + tx] = f2b(t[tx][ty + j * 8]);
}

// ---------------------------------------------------------------------------
// RMSNorm (standalone, for x2 -> h2b)
// ---------------------------------------------------------------------------
__global__ __launch_bounds__(256)
void rmsnorm_k(const float* __restrict__ x, const float* __restrict__ w,
               u16* __restrict__ out) {
    const int row = blockIdx.x;
    const int tid = threadIdx.x;
    const float4 v = ((const float4*)(x + (size_t)row * D_MODEL))[tid];
    float ss = v.x * v.x + v.y * v.y + v.z * v.z + v.w * v.w;
    for (int o = 32; o; o >>= 1) ss += __shfl_down(ss, o);
    __shared__ float red[4];
    if ((tid & 63) == 0) red[tid >> 6] = ss;
    __syncthreads();
    const float tot = red[0] + red[1] + red[2] + red[3];
    const float rs = rsqrtf(tot * (1.0f / D_MODEL) + 1e-6f);
    const float4 wv = ((const float4*)w)[tid];
    u16* op = out + (size_t)row * D_MODEL + tid * 4;
    u32 p0 = (u32)f2b(v.x * rs * wv.x) | ((u32)f2b(v.y * rs * wv.y) << 16);
    u32 p1 = (u32)f2b(v.z * rs * wv.z) | ((u32)f2b(v.w * rs * wv.w) << 16);
    uint2 pk; pk.x = p0; pk.y = p1;
    *(uint2*)op = pk;
}

// ---------------------------------------------------------------------------
// QKV GEMM + fused pack epilogue (replaces gemm128<0> + packkv_k).
// Loop identical to the verified BK=64 + XOR-swizzle gemm128. Per-region
// epilogue on n0 (block-uniform):
//   n0 <  1024: Q  -> qkvb (raw, flash reads Q from here)
//   n0 < 2048:  K  -> RoPE in-register (partner element is in the adjacent
//               lane: d-parity == r16-parity, so __shfl_xor(v,1) provides
//               it; angle fi = s*32 + (d>>1)) -> kp[h][s][d]
//   else:       V  -> 128x128 LDS transpose (reuse staging LDS, [128][136]
//               pad: 16B-aligned rows, banks spread) -> coalesced 32B
//               stores to vt[h][d][s]
// Removes packkv_k's 33MB round-trip + one launch. LDS = 34 KB.
// ---------------------------------------------------------------------------
__global__ __launch_bounds__(256)
void gemm_qkv(const u16* __restrict__ A, int lda, const u16* __restrict__ Bt, int ldb,
              u16* __restrict__ C, int ldc, int K,
              const float* __restrict__ fc, const float* __restrict__ fs,
              u16* __restrict__ kp, u16* __restrict__ vtb) {
    const int m0 = blockIdx.y * 128, n0 = blockIdx.x * 128;
    const int tid = threadIdx.x;
    const int wave = tid >> 6, lane = tid & 63;
    const int wr = wave >> 1, wc = wave & 1;
    const int r16 = lane & 15, kq = lane >> 4;

    __shared__ __align__(16) u16 S[128 * 136];   // As | Bs, reused as V-transpose tile
    u16* const As = S;
    u16* const Bs = S + 8192;

    const int srow = tid >> 3;                       // 0..31
    const int scol = ((tid & 7) ^ (srow & 7)) * 8;   // pre-swizzled source col
    const u16* ag0 = A + (size_t)(m0 +  0 + srow) * lda + scol;
    const u16* ag1 = A + (size_t)(m0 + 32 + srow) * lda + scol;
    const u16* ag2 = A + (size_t)(m0 + 64 + srow) * lda + scol;
    const u16* ag3 = A + (size_t)(m0 + 96 + srow) * lda + scol;
    const u16* bg0 = Bt + (size_t)(n0 +  0 + srow) * ldb + scol;
    const u16* bg1 = Bt + (size_t)(n0 + 32 + srow) * ldb + scol;
    const u16* bg2 = Bt + (size_t)(n0 + 64 + srow) * ldb + scol;
    const u16* bg3 = Bt + (size_t)(n0 + 96 + srow) * ldb + scol;
    u16* const ad = As + tid * 8;
    u16* const bd = Bs + tid * 8;

    f32x4 acc[16];
#pragma unroll
    for (int i = 0; i < 16; ++i) acc[i] = f32x4{0.f, 0.f, 0.f, 0.f};

    const int rsw = r16 & 7;
    for (int k0 = 0; k0 < K; k0 += 64) {
        __syncthreads();
        gll16(ag0 + k0, ad);
        gll16(ag1 + k0, ad + 2048);
        gll16(ag2 + k0, ad + 4096);
        gll16(ag3 + k0, ad + 6144);
        gll16(bg0 + k0, bd);
        gll16(bg1 + k0, bd + 2048);
        gll16(bg2 + k0, bd + 4096);
        gll16(bg3 + k0, bd + 6144);
        __syncthreads();
#pragma unroll
        for (int ks = 0; ks < 2; ++ks) {
            const int slot = (((ks << 2) | kq) ^ rsw) * 8;
            bf16x8 af[4], bf[4];
#pragma unroll
            for (int mt = 0; mt < 4; ++mt)
                af[mt] = *(const bf16x8*)&As[(wr * 64 + mt * 16 + r16) * 64 + slot];
#pragma unroll
            for (int nt = 0; nt < 4; ++nt)
                bf[nt] = *(const bf16x8*)&Bs[(wc * 64 + nt * 16 + r16) * 64 + slot];
#pragma unroll
            for (int mt = 0; mt < 4; ++mt)
#pragma unroll
                for (int nt = 0; nt < 4; ++nt)
                    acc[mt * 4 + nt] = MFMA16(af[mt], bf[nt], acc[mt * 4 + nt], 0, 0, 0);
        }
    }

    if (n0 < D_MODEL) {
        // ---- Q region: raw bf16 write to qkvb ----
#pragma unroll
        for (int mt = 0; mt < 4; ++mt)
#pragma unroll
            for (int nt = 0; nt < 4; ++nt) {
                const int col = n0 + wc * 64 + nt * 16 + r16;
#pragma unroll
                for (int j = 0; j < 4; ++j) {
                    const int row = m0 + wr * 64 + mt * 16 + kq * 4 + j;
                    C[(size_t)row * ldc + col] = f2b(acc[mt * 4 + nt][j]);
                }
            }
    } else if (n0 < 2 * D_MODEL) {
        // ---- K region: fused RoPE -> kp[h][s][d] ----
#pragma unroll
        for (int mt = 0; mt < 4; ++mt)
#pragma unroll
            for (int nt = 0; nt < 4; ++nt) {
                const int kcol = n0 - D_MODEL + wc * 64 + nt * 16 + r16;
                const int h = kcol >> 6, d = kcol & 63;
#pragma unroll
                for (int j = 0; j < 4; ++j) {
                    const int row = m0 + wr * 64 + mt * 16 + kq * 4 + j;
                    const float v = acc[mt * 4 + nt][j];
                    const float p = __shfl_xor(v, 1);
                    const int fi = row * 32 + (d >> 1);
                    const float cc = fc[fi], ss = fs[fi];
                    const float o = (d & 1) ? (p * ss + v * cc) : (v * cc - p * ss);
                    kp[((size_t)h * S_LEN + row) * DK + d] = f2b(o);
                }
            }
    } else {
        // ---- V region: LDS transpose -> vt[h][d][s] ----
        __syncthreads();   // all waves done reading As/Bs before overwrite
#pragma unroll
        for (int mt = 0; mt < 4; ++mt)
#pragma unroll
            for (int nt = 0; nt < 4; ++nt) {
                const int dl = wc * 64 + nt * 16 + r16;
                const int sl = wr * 64 + mt * 16 + kq * 4;
                uint2 pk;
                pk.x = (u32)f2b(acc[mt * 4 + nt][0]) |
                       ((u32)f2b(acc[mt * 4 + nt][1]) << 16);
                pk.y = (u32)f2b(acc[mt * 4 + nt][2]) |
                       ((u32)f2b(acc[mt * 4 + nt][3]) << 16);
                *(uint2*)&S[dl * 136 + sl] = pk;
            }
        __syncthreads();
#pragma unroll
        for (int it = 0; it < 4; ++it) {
            const int dl = wave * 8 + (lane >> 3) + it * 32;
            const int so = (lane & 7) * 16;
            const uint4 a = *(const uint4*)&S[dl * 136 + so];
            const uint4 b = *(const uint4*)&S[dl * 136 + so + 8];
            const int vcol = n0 - 2 * D_MODEL + dl;
            const int h = vcol >> 6, d = vcol & 63;
            u16* dst = vtb + (size_t)h * DK * S_LEN + (size_t)d * S_LEN + m0 + so;
            *(uint4*)dst = a;
            *(uint4*)(dst + 8) = b;
        }
    }
}

// ---------------------------------------------------------------------------
// 128(M) x 64(N) GEMM + fp32 residual epilogue, BK=64 + XOR-swizzle
// (verified round 6). LDS = 16 + 8 = 24 KB.
// ---------------------------------------------------------------------------
__global__ __launch_bounds__(256)
void gemm64r(const u16* __restrict__ A, int lda, const u16* __restrict__ Bt, int ldb,
             float* __restrict__ C, int ldc, int K, const float* __restrict__ resid) {
    const int m0 = blockIdx.y * 128, n0 = blockIdx.x * 64;
    const int tid = threadIdx.x;
    const int wave = tid >> 6, lane = tid & 63;
    const int r16 = lane & 15, kq = lane >> 4;

    __shared__ __align__(16) u16 As[128 * 64];
    __shared__ __align__(16) u16 Bs[64 * 64];

    const int srow = tid >> 3;
    const int scol = ((tid & 7) ^ (srow & 7)) * 8;
    const u16* ag0 = A + (size_t)(m0 +  0 + srow) * lda + scol;
    const u16* ag1 = A + (size_t)(m0 + 32 + srow) * lda + scol;
    const u16* ag2 = A + (size_t)(m0 + 64 + srow) * lda + scol;
    const u16* ag3 = A + (size_t)(m0 + 96 + srow) * lda + scol;
    const u16* bg0 = Bt + (size_t)(n0 +  0 + srow) * ldb + scol;
    const u16* bg1 = Bt + (size_t)(n0 + 32 + srow) * ldb + scol;
    u16* const ad = As + tid * 8;
    u16* const bd = Bs + tid * 8;

    f32x4 acc[8];
#pragma unroll
    for (int i = 0; i < 8; ++i) acc[i] = f32x4{0.f, 0.f, 0.f, 0.f};

    const int rsw = r16 & 7;
    for (int k0 = 0; k0 < K; k0 += 64) {
        __syncthreads();
        gll16(ag0 + k0, ad);
        gll16(ag1 + k0, ad + 2048);
        gll16(ag2 + k0, ad + 4096);
        gll16(ag3 + k0, ad + 6144);
        gll16(bg0 + k0, bd);
        gll16(bg1 + k0, bd + 2048);
        __syncthreads();
#pragma unroll
        for (int ks = 0; ks < 2; ++ks) {
            const int slot = (((ks << 2) | kq) ^ rsw) * 8;
            bf16x8 af[2], bf[4];
#pragma unroll
            for (int mt = 0; mt < 2; ++mt)
                af[mt] = *(const bf16x8*)&As[(wave * 32 + mt * 16 + r16) * 64 + slot];
#pragma unroll
            for (int nt = 0; nt < 4; ++nt)
                bf[nt] = *(const bf16x8*)&Bs[(nt * 16 + r16) * 64 + slot];
#pragma unroll
            for (int mt = 0; mt < 2; ++mt)
#pragma unroll
                for (int nt = 0; nt < 4; ++nt)
                    acc[mt * 4 + nt] = MFMA16(af[mt], bf[nt], acc[mt * 4 + nt], 0, 0, 0);
        }
    }

#pragma unroll
    for (int mt = 0; mt < 2; ++mt)
#pragma unroll
        for (int nt = 0; nt < 4; ++nt) {
            const int col = n0 + nt * 16 + r16;
#pragma unroll
            for (int j = 0; j < 4; ++j) {
                const int row = m0 + wave * 32 + mt * 16 + kq * 4 + j;
                C[(size_t)row * ldc + col] =
                    resid[(size_t)row * ldc + col] + acc[mt * 4 + nt][j];
            }
        }
}

// ---------------------------------------------------------------------------
// FFN dual GEMM v3: tile 128(M) x 96(N per matrix), BK=64 (verified win).
// ---------------------------------------------------------------------------
__global__ __launch_bounds__(256, 3)
void gemm_dual96x(const u16* __restrict__ A, int lda,
                  const u16* __restrict__ B1, const u16* __restrict__ B3, int ldb,
                  u16* __restrict__ C, int ldc, int K) {
    const int m0 = blockIdx.y * 128, n0 = blockIdx.x * 96;
    const int tid = threadIdx.x;
    const int wave = tid >> 6, lane = tid & 63;
    const int wr = wave >> 1, wc = wave & 1;
    const int r16 = lane & 15, kq = lane >> 4;

    __shared__ __align__(16) u16 As[128 * 64];   // swizzled rows
    __shared__ __align__(16) u16 Bs[192 * 64];   // rows 0-95 = B1, 96-191 = B3

    const int srow = tid >> 3;                       // 0..31 (row within call)
    const int scol = ((tid & 7) ^ (srow & 7)) * 8;   // pre-swizzled source col
    const u16* ag0 = A + (size_t)(m0 +  0 + srow) * lda + scol;
    const u16* ag1 = A + (size_t)(m0 + 32 + srow) * lda + scol;
    const u16* ag2 = A + (size_t)(m0 + 64 + srow) * lda + scol;
    const u16* ag3 = A + (size_t)(m0 + 96 + srow) * lda + scol;
    const u16* bg0 = B1 + (size_t)(n0 +  0 + srow) * ldb + scol;
    const u16* bg1 = B1 + (size_t)(n0 + 32 + srow) * ldb + scol;
    const u16* bg2 = B1 + (size_t)(n0 + 64 + srow) * ldb + scol;
    const u16* bg3 = B3 + (size_t)(n0 +  0 + srow) * ldb + scol;
    const u16* bg4 = B3 + (size_t)(n0 + 32 + srow) * ldb + scol;
    const u16* bg5 = B3 + (size_t)(n0 + 64 + srow) * ldb + scol;
    u16* const ad = As + tid * 8;
    u16* const bd = Bs + tid * 8;

    f32x4 acc1[12], acc3[12];
#pragma unroll
    for (int i = 0; i < 12; ++i) {
        acc1[i] = f32x4{0.f, 0.f, 0.f, 0.f};
        acc3[i] = f32x4{0.f, 0.f, 0.f, 0.f};
    }

    const int rsw = r16 & 7;
    for (int k0 = 0; k0 < K; k0 += 64) {
        __syncthreads();
        gll16(ag0 + k0, ad);
        gll16(ag1 + k0, ad + 2048);
        gll16(ag2 + k0, ad + 4096);
        gll16(ag3 + k0, ad + 6144);
        gll16(bg0 + k0, bd);
        gll16(bg1 + k0, bd + 2048);
        gll16(bg2 + k0, bd + 4096);
        gll16(bg3 + k0, bd + 6144);
        gll16(bg4 + k0, bd + 8192);
        gll16(bg5 + k0, bd + 10240);
        __syncthreads();
#pragma unroll
        for (int ks = 0; ks < 2; ++ks) {
            const int slot = (((ks << 2) | kq) ^ rsw) * 8;
            bf16x8 af[4], b1f[3], b3f[3];
#pragma unroll
            for (int mt = 0; mt < 4; ++mt)
                af[mt] = *(const bf16x8*)&As[(wr * 64 + mt * 16 + r16) * 64 + slot];
#pragma unroll
            for (int nt = 0; nt < 3; ++nt) {
                b1f[nt] = *(const bf16x8*)&Bs[(wc * 48 + nt * 16 + r16) * 64 + slot];
                b3f[nt] = *(const bf16x8*)&Bs[(96 + wc * 48 + nt * 16 + r16) * 64 + slot];
            }
#pragma unroll
            for (int mt = 0; mt < 4; ++mt)
#pragma unroll
                for (int nt = 0; nt < 3; ++nt) {
                    acc1[mt * 3 + nt] = MFMA16(af[mt], b1f[nt], acc1[mt * 3 + nt], 0, 0, 0);
                    acc3[mt * 3 + nt] = MFMA16(af[mt], b3f[nt], acc3[mt * 3 + nt], 0, 0, 0);
                }
        }
    }

#pragma unroll
    for (int mt = 0; mt < 4; ++mt)
#pragma unroll
        for (int nt = 0; nt < 3; ++nt) {
            const int col = n0 + wc * 48 + nt * 16 + r16;
#pragma unroll
            for (int j = 0; j < 4; ++j) {
                const int row = m0 + wr * 64 + mt * 16 + kq * 4 + j;
                const float v1 = acc1[mt * 3 + nt][j];
                const float v3 = acc3[mt * 3 + nt][j];
                const float sig = 1.0f / (1.0f + __expf(-v1));
                C[(size_t)row * ldc + col] = f2b(v1 * sig * v3);
            }
        }
}

// ---------------------------------------------------------------------------
// Flash attention v11 (verified 68 us): causal pairing, KVBLK=128, fused
// dual-q tile. LDS = 2*16(K) + 2*16(V) + 2*8(Ps) = 80 KB -> 2 blocks/CU.
// ---------------------------------------------------------------------------
__global__ __launch_bounds__(256)
void flash_k(const u16* __restrict__ qkv, const u16* __restrict__ vt,
             const u16* __restrict__ kp, const float* __restrict__ fc,
             const float* __restrict__ fs, u16* __restrict__ ctx) {
    const int h = blockIdx.x;
    const int pair = blockIdx.y;       // 0..31
    const int qa = pair, qb = 63 - pair;
    const int tid = threadIdx.x;
    const int wave = tid >> 6, lane = tid & 63;
    const int r16 = lane & 15, kq = lane >> 4;

    __shared__ __align__(16) u16 Kb[2][2 * 64 * 64];   // [buf][sub 64-tile]
    __shared__ __align__(16) u16 Vb[2][2 * 64 * 64];
    __shared__ __align__(16) u16 PsB[4 * 16 * 64];     // per-wave [q][kv]
    __shared__ __align__(16) u16 PsA[4 * 16 * 64];

    const u16* kb = kp + (size_t)h * S_LEN * DK;
    const u16* vb = vt + (size_t)h * DK * S_LEN;
    const int srow = tid >> 3;
    const int lcol = ((tid & 7) ^ (srow & 7)) * 8;
    const int qloc = wave * 16 + r16;
    const int sw = r16 & 7;
    const int c0 = (kq ^ sw) * 8;
    const int c1 = ((4 ^ kq) ^ sw) * 8;
    const int psw = r16 & 14;
    u16* psB = PsB + wave * 1024 + r16 * 64;
    u16* psA = PsA + wave * 1024 + r16 * 64;

    const float SC = 0.125f * 1.44269504f;
    auto rp = [SC](u32 w, float c, float s) -> u32 {
        const float a = b2f((u16)w), b = b2f((u16)(w >> 16));
        return (u32)f2b((a * c - b * s) * SC) |
               ((u32)f2b((a * s + b * c) * SC) << 16);
    };
    // Q: raw load + RoPE + scale, in registers (for both q-tiles)
    auto loadq = [&](int qglob, bf16x8& q0out, bf16x8& q1out) {
        const u16* qrow = qkv + (size_t)qglob * QKV_LD + h * DK;
        uint4 uq0 = *(const uint4*)(qrow + kq * 8);
        uint4 uq1 = *(const uint4*)(qrow + 32 + kq * 8);
        const float4 c0v = *(const float4*)(fc + qglob * 32 + kq * 4);
        const float4 s0v = *(const float4*)(fs + qglob * 32 + kq * 4);
        const float4 c1v = *(const float4*)(fc + qglob * 32 + 16 + kq * 4);
        const float4 s1v = *(const float4*)(fs + qglob * 32 + 16 + kq * 4);
        uq0.x = rp(uq0.x, c0v.x, s0v.x); uq0.y = rp(uq0.y, c0v.y, s0v.y);
        uq0.z = rp(uq0.z, c0v.z, s0v.z); uq0.w = rp(uq0.w, c0v.w, s0v.w);
        uq1.x = rp(uq1.x, c1v.x, s1v.x); uq1.y = rp(uq1.y, c1v.y, s1v.y);
        uq1.z = rp(uq1.z, c1v.z, s1v.z); uq1.w = rp(uq1.w, c1v.w, s1v.w);
        q0out = __builtin_bit_cast(bf16x8, uq0);
        q1out = __builtin_bit_cast(bf16x8, uq1);
    };
    const int qgA = qa * 64 + qloc;
    const int qgB = qb * 64 + qloc;
    bf16x8 qfA0, qfA1, qfB0, qfB1;
    loadq(qgA, qfA0, qfA1);
    loadq(qgB, qfB0, qfB1);

    f32x4 oA[4], oB[4];
#pragma unroll
    for (int i = 0; i < 4; ++i) {
        oA[i] = f32x4{0.f, 0.f, 0.f, 0.f};
        oB[i] = f32x4{0.f, 0.f, 0.f, 0.f};
    }
    f32x4 laccA = f32x4{0.f, 0.f, 0.f, 0.f};
    f32x4 laccB = f32x4{0.f, 0.f, 0.f, 0.f};
    const uint4 uone = make_uint4(0x3F803F80u, 0x3F803F80u, 0x3F803F80u, 0x3F803F80u);
    const bf16x8 ones = __builtin_bit_cast(bf16x8, uone);

    // single-q tile (B only): S^T = K.Q^T -> p=2^s -> packed P^T -> PV
    auto tile_single = [&](const u16* Ks, const u16* Vs, bool dmask) {
        f32x4 s[4];
#pragma unroll
        for (int nt = 0; nt < 4; ++nt) {
            s[nt] = f32x4{0.f, 0.f, 0.f, 0.f};
            const bf16x8 k0 = *(const bf16x8*)&Ks[(nt * 16 + r16) * 64 + c0];
            s[nt] = MFMA16(k0, qfB0, s[nt], 0, 0, 0);
            const bf16x8 k1 = *(const bf16x8*)&Ks[(nt * 16 + r16) * 64 + c1];
            s[nt] = MFMA16(k1, qfB1, s[nt], 0, 0, 0);
        }
        float pr[16];
#pragma unroll
        for (int nt = 0; nt < 4; ++nt)
#pragma unroll
            for (int j = 0; j < 4; ++j) pr[nt * 4 + j] = EXP2(s[nt][j]);
        if (dmask) {
#pragma unroll
            for (int nt = 0; nt < 4; ++nt)
#pragma unroll
                for (int j = 0; j < 4; ++j)
                    if ((nt * 16 + kq * 4 + j) > qloc) pr[nt * 4 + j] = 0.f;
        }
#pragma unroll
        for (int nt = 0; nt < 4; ++nt) {
            uint2 pk;
            pk.x = pk_trunc(pr[nt * 4 + 0], pr[nt * 4 + 1]);
            pk.y = pk_trunc(pr[nt * 4 + 2], pr[nt * 4 + 3]);
            *(uint2*)&psB[((nt * 4 + kq) ^ psw) * 4] = pk;
        }
#pragma unroll
        for (int ks = 0; ks < 2; ++ks) {
            const bf16x8 pf = *(const bf16x8*)&psB[((8 * ks + 2 * kq) ^ psw) * 4];
            laccB = MFMA16(ones, pf, laccB, 0, 0, 0);
            const int cv = (((ks << 2) ^ kq) ^ sw) * 8;
#pragma unroll
            for (int nt = 0; nt < 4; ++nt) {
                const bf16x8 vf = *(const bf16x8*)&Vs[(nt * 16 + r16) * 64 + cv];
                oB[nt] = MFMA16(vf, pf, oB[nt], 0, 0, 0);
            }
        }
    };

    // fused dual-q tile: each K/V fragment loaded ONCE, feeds both q-tiles.
    // B is never diag-masked here (t <= qa < qb); A masked when t == qa.
    auto tile_dual = [&](const u16* Ks, const u16* Vs, bool maskA) {
        f32x4 sB[4], sA[4];
#pragma unroll
        for (int nt = 0; nt < 4; ++nt) {
            sB[nt] = f32x4{0.f, 0.f, 0.f, 0.f};
            sA[nt] = f32x4{0.f, 0.f, 0.f, 0.f};
            const bf16x8 k0 = *(const bf16x8*)&Ks[(nt * 16 + r16) * 64 + c0];
            sB[nt] = MFMA16(k0, qfB0, sB[nt], 0, 0, 0);
            sA[nt] = MFMA16(k0, qfA0, sA[nt], 0, 0, 0);
            const bf16x8 k1 = *(const bf16x8*)&Ks[(nt * 16 + r16) * 64 + c1];
            sB[nt] = MFMA16(k1, qfB1, sB[nt], 0, 0, 0);
            sA[nt] = MFMA16(k1, qfA1, sA[nt], 0, 0, 0);
        }
        float prB[16], prA[16];
#pragma unroll
        for (int nt = 0; nt < 4; ++nt)
#pragma unroll
            for (int j = 0; j < 4; ++j) {
                prB[nt * 4 + j] = EXP2(sB[nt][j]);
                prA[nt * 4 + j] = EXP2(sA[nt][j]);
            }
        if (maskA) {
#pragma unroll
            for (int nt = 0; nt < 4; ++nt)
#pragma unroll
                for (int j = 0; j < 4; ++j)
                    if ((nt * 16 + kq * 4 + j) > qloc) prA[nt * 4 + j] = 0.f;
        }
#pragma unroll
        for (int nt = 0; nt < 4; ++nt) {
            uint2 pkB, pkA;
            pkB.x = pk_trunc(prB[nt * 4 + 0], prB[nt * 4 + 1]);
            pkB.y = pk_trunc(prB[nt * 4 + 2], prB[nt * 4 + 3]);
            pkA.x = pk_trunc(prA[nt * 4 + 0], prA[nt * 4 + 1]);
            pkA.y = pk_trunc(prA[nt * 4 + 2], prA[nt * 4 + 3]);
            *(uint2*)&psB[((nt * 4 + kq) ^ psw) * 4] = pkB;
            *(uint2*)&psA[((nt * 4 + kq) ^ psw) * 4] = pkA;
        }
#pragma unroll
        for (int ks = 0; ks < 2; ++ks) {
            const bf16x8 pfB = *(const bf16x8*)&psB[((8 * ks + 2 * kq) ^ psw) * 4];
            const bf16x8 pfA = *(const bf16x8*)&psA[((8 * ks + 2 * kq) ^ psw) * 4];
            laccB = MFMA16(ones, pfB, laccB, 0, 0, 0);
            laccA = MFMA16(ones, pfA, laccA, 0, 0, 0);
            const int cv = (((ks << 2) ^ kq) ^ sw) * 8;
#pragma unroll
            for (int nt = 0; nt < 4; ++nt) {
                const bf16x8 vf = *(const bf16x8*)&Vs[(nt * 16 + r16) * 64 + cv];
                oB[nt] = MFMA16(vf, pfB, oB[nt], 0, 0, 0);
                oA[nt] = MFMA16(vf, pfA, oA[nt], 0, 0, 0);
            }
        }
    };

    // stage one 64-kv tile t into (kd, vd)
    auto stage = [&](int t, u16* kd, u16* vd) {
        const int tb = t * 64;
#pragma unroll
        for (int i = 0; i < 2; ++i) {
            const int r = srow + i * 32;
            gll16(kb + (size_t)(tb + r) * DK + lcol, kd + tid * 8 + i * 2048);
            gll16(vb + (size_t)r * S_LEN + tb + lcol, vd + tid * 8 + i * 2048);
        }
    };

    // preload tiles 0,1 into buffer 0 (qb >= 32, so tile 1 always exists)
    stage(0, Kb[0], Vb[0]);
    stage(1, Kb[0] + 4096, Vb[0] + 4096);

    const int nT = (qb + 2) >> 1;      // ceil((qb+1)/2) iterations
    for (int T = 0; T < nT; ++T) {
        __syncthreads();   // drains this iteration's buffer; prev buffer free
        const int nb = (T + 1) * 2;
        if (nb <= qb) {    // prefetch tiles nb, nb+1 into the other buffer
            u16* kd = ((T + 1) & 1) ? Kb[1] : Kb[0];
            u16* vd = ((T + 1) & 1) ? Vb[1] : Vb[0];
            stage(nb, kd, vd);
            if (nb + 1 <= qb) stage(nb + 1, kd + 4096, vd + 4096);
        }
        const u16* Ks = (T & 1) ? Kb[1] : Kb[0];
        const u16* Vs = (T & 1) ? Vb[1] : Vb[0];

        // subtile 0: t = 2T (always <= qb since T < nT)
        {
            const int t = 2 * T;
            if (t <= qa) tile_dual(Ks, Vs, t == qa);
            else         tile_single(Ks, Vs, t == qb);
        }
        // subtile 1: t = 2T+1 (may exceed qb on the last iteration)
        if (2 * T + 1 <= qb) {
            const int t = 2 * T + 1;
            if (t <= qa) tile_dual(Ks + 4096, Vs + 4096, t == qa);
            else         tile_single(Ks + 4096, Vs + 4096, t == qb);
        }
    }

    // l: every lacc element equals the full sum for column q=r16
    auto wout = [&](f32x4 (&o)[4], float lsum, int qg) {
        const float inv = 1.0f / lsum;
        const size_t row = qg;
#pragma unroll
        for (int nt = 0; nt < 4; ++nt) {
            uint2 pk;
            pk.x = (u32)f2b(o[nt][0] * inv) | ((u32)f2b(o[nt][1] * inv) << 16);
            pk.y = (u32)f2b(o[nt][2] * inv) | ((u32)f2b(o[nt][3] * inv) << 16);
            *(uint2*)&ctx[row * D_MODEL + h * DK + nt * 16 + kq * 4] = pk;
        }
    };
    wout(oA, laccA[0], qgA);
    wout(oB, laccB[0], qgB);
}

// ---------------------------------------------------------------------------
extern "C" void kernel_launch(void* const* d_in, const int* in_sizes, int n_in,
                              void* d_out, int out_size, void* d_ws, size_t ws_size,
                              hipStream_t stream) {
    const float* x    = (const float*)d_in[0];
    const float* fcos = (const float*)d_in[1];
    const float* fsin = (const float*)d_in[2];
    const float* Wq = (const float*)d_in[4];
    const float* Wk = (const float*)d_in[5];
    const float* Wv = (const float*)d_in[6];
    const float* Wo = (const float*)d_in[7];
    const float* ln1 = (const float*)d_in[8];
    const float* ln2 = (const float*)d_in[9];
    const float* w1 = (const float*)d_in[10];
    const float* w2 = (const float*)d_in[11];
    const float* w3 = (const float*)d_in[12];
    float* out = (float*)d_out;

    char* ws = (char*)d_ws;
    size_t off = 0;
    auto alloc = [&](size_t bytes) -> char* {
        char* p = ws + off;
        off += (bytes + 255) & ~(size_t)255;
        return p;
    };
    u16* hb    = (u16*)alloc((size_t)S_LEN * D_MODEL * 2);
    u16* wqkvt = (u16*)alloc((size_t)QKV_LD * D_MODEL * 2);  // [3072][1024]
    u16* wot   = (u16*)alloc((size_t)D_MODEL * D_MODEL * 2);
    u16* qkvb  = (u16*)alloc((size_t)S_LEN * QKV_LD * 2);    // [4096][3072] (Q region live)
    u16* vt    = (u16*)alloc((size_t)S_LEN * D_MODEL * 2);   // [H][DK][S]
    u16* kpack = (u16*)alloc((size_t)S_LEN * D_MODEL * 2);   // [H][S][DK]
    u16* ctxb  = (u16*)alloc((size_t)S_LEN * D_MODEL * 2);
    float* x2  = (float*)alloc((size_t)S_LEN * D_MODEL * 4);
    u16* h2b   = (u16*)alloc((size_t)S_LEN * D_MODEL * 2);
    u16* w1t   = (u16*)alloc((size_t)HIDP * D_MODEL * 2);    // [2880][1024]
    u16* w3t   = (u16*)alloc((size_t)HIDP * D_MODEL * 2);
    u16* w2t   = (u16*)alloc((size_t)D_MODEL * HIDP * 2);    // [1024][2880]
    u16* ffb   = (u16*)alloc((size_t)S_LEN * HIDP * 2);      // [4096][2880]

    // weight transposes + rmsnorm(x, ln1), one launch
    prep_k<<<16832, 256, 0, stream>>>(
        Wq, Wk, Wv, Wo, w1, w3, w2,
        wqkvt, wqkvt + (size_t)D_MODEL * D_MODEL,
        wqkvt + (size_t)2 * D_MODEL * D_MODEL, wot, w1t, w3t, w2t,
        x, ln1, hb);

    // QKV = h @ [Wq|Wk|Wv] with fused pack epilogue:
    //   Q -> qkvb raw; K -> RoPE -> kpack; V -> transpose -> vt
    gemm_qkv<<<dim3(QKV_LD / 128, S_LEN / 128), 256, 0, stream>>>(
        hb, D_MODEL, wqkvt, D_MODEL, qkvb, QKV_LD, D_MODEL,
        fcos, fsin, kpack, vt);

    // flash attention (Q RoPE fused; causal pairing, KVBLK=128, fused dual-q)
    flash_k<<<dim3(NHEAD, 32), 256, 0, stream>>>(qkvb, vt, kpack, fcos, fsin, ctxb);

    // x2 = x + ctx @ Wo
    gemm64r<<<dim3(D_MODEL / 64, S_LEN / 128), 256, 0, stream>>>(
        ctxb, D_MODEL, wot, D_MODEL, x2, D_MODEL, D_MODEL, x);

    // h2 = rmsnorm(x2, ln2)
    rmsnorm_k<<<S_LEN, 256, 0, stream>>>(x2, ln2, h2b);

    // ff = silu(h2@w1) * (h2@w3)
    gemm_dual96x<<<dim3(HIDP / 96, S_LEN / 128), 256, 0, stream>>>(
        h2b, D_MODEL, w1t, w3t, D_MODEL, ffb, HIDP, D_MODEL);

    // out = x2 + ff @ w2
    gemm64r<<<dim3(D_MODEL / 64, S_LEN / 128), 256, 0, stream>>>(
        ffb, HIDP, w2t, HIDP, out, D_MODEL, HIDP, x2);
}